// Round 6
// baseline (190.570 us; speedup 1.0000x reference)
//
#include <hip/hip_runtime.h>

#define DD 256      // embed dim
#define NH 8        // heads
#define NP 1024     // patches
#define NQ 64       // query embeddings
#define SCALE 0.17677669529663687f

typedef float f32x4 __attribute__((ext_vector_type(4)));

__device__ __forceinline__ float wred_sum(float p) {
  #pragma unroll
  for (int m = 32; m; m >>= 1) p += __shfl_xor(p, m);
  return p;
}
__device__ __forceinline__ float wred_max(float p) {
  #pragma unroll
  for (int m = 32; m; m >>= 1) p = fmaxf(p, __shfl_xor(p, m));
  return p;
}
__device__ __forceinline__ float red8(float p) {
  p += __shfl_xor(p, 1);
  p += __shfl_xor(p, 2);
  p += __shfl_xor(p, 4);
  return p;
}
__device__ __forceinline__ float dot4(float4 a, float4 b) {
  return a.x*b.x + a.y*b.y + a.z*b.z + a.w*b.w;
}
// nontemporal float4 load (evict-first: don't pollute L2 with streamed weights)
__device__ __forceinline__ float4 ldnt4(const float* p) {
  f32x4 v = __builtin_nontemporal_load((const f32x4*)p);
  return make_float4(v.x, v.y, v.z, v.w);
}
__device__ __forceinline__ void preload8(const float* x, int lane, float4* xf) {
  const int o = (lane & 7) * 4;
  #pragma unroll
  for (int cc = 0; cc < 8; ++cc) xf[cc] = *(const float4*)&x[cc*32 + o];
}
// 16 rows per pass: rows r0+(lane>>3), r0+8+(lane>>3); 16 dwordx4 in flight.
template<bool NT>
__device__ __forceinline__ void pass16(const float* __restrict__ W, int ldk,
                                       int r0, int lane, const float4* xf,
                                       float* outA, float* outB) {
  const float* baseA = W + (size_t)(r0 + (lane >> 3))*ldk + (lane & 7)*4;
  const float* baseB = baseA + (size_t)8*ldk;
  float4 wa[8], wb[8];
  #pragma unroll
  for (int cc = 0; cc < 8; ++cc) wa[cc] = NT ? ldnt4(&baseA[cc*32]) : *(const float4*)&baseA[cc*32];
  #pragma unroll
  for (int cc = 0; cc < 8; ++cc) wb[cc] = NT ? ldnt4(&baseB[cc*32]) : *(const float4*)&baseB[cc*32];
  float a = 0.f, b = 0.f;
  #pragma unroll
  for (int cc = 0; cc < 8; ++cc) { a += dot4(wa[cc], xf[cc]); b += dot4(wb[cc], xf[cc]); }
  *outA = red8(a); *outB = red8(b);
}

// layernorm over a 256-float LDS buffer -> outp; caller must __syncthreads() after.
__device__ __forceinline__ void layernorm_store(const float* buf, float* outp,
                                                const float* g, const float* b,
                                                float* red, int tid, int wid, int lane)
{
  __syncthreads();
  if (wid == 0) {
    float s = buf[lane] + buf[lane+64] + buf[lane+128] + buf[lane+192];
    s = wred_sum(s);
    if (!lane) red[0] = s * (1.f/256.f);
  }
  __syncthreads();
  float mn = red[0];
  if (wid == 0) {
    float d0 = buf[lane]-mn, d1 = buf[lane+64]-mn, d2 = buf[lane+128]-mn, d3 = buf[lane+192]-mn;
    float s = d0*d0 + d1*d1 + d2*d2 + d3*d3;
    s = wred_sum(s);
    if (!lane) red[1] = rsqrtf(s * (1.f/256.f) + 1e-5f);
  }
  __syncthreads();
  if (tid < 256) outp[tid] = (buf[tid] - mn) * red[1] * g[tid] + b[tid];
}

// ---------------- K1: patches transpose (blocks 0-255) + kvq (blocks 256-319) ----------------
__global__ __launch_bounds__(256)
void k_pre(const float* __restrict__ patches, float* __restrict__ pT,
           const float* __restrict__ qe, const float* __restrict__ Wqkv_q,
           const float* __restrict__ bqkv_q, float* __restrict__ kvq)
{
  const int b = blockIdx.x, tid = threadIdx.x;
  __shared__ float tile[32][33];
  __shared__ float x[DD], kvrow[512];
  if (b < 256) {
    const int pb = (b & 31)*32, cb = (b >> 5)*32;
    const int tx = tid & 31, ty = tid >> 5;
    #pragma unroll
    for (int i = 0; i < 4; ++i)
      tile[ty + i*8][tx] = patches[(size_t)(pb + ty + i*8)*DD + cb + tx];
    __syncthreads();
    #pragma unroll
    for (int i = 0; i < 4; ++i)
      pT[(size_t)(cb + ty + i*8)*NP + pb + tx] = tile[tx][ty + i*8];
  } else {
    const int j = b - 256, w = tid >> 6, lane = tid & 63;
    if (tid < DD) x[tid] = qe[j*DD + tid];
    __syncthreads();
    float4 xf[8]; preload8(x, lane, xf);
    #pragma unroll
    for (int g = 0; g < 8; ++g) {
      int r0 = w*128 + g*16;
      float a, bb;
      pass16<false>(Wqkv_q + (size_t)DD*DD, DD, r0, lane, xf, &a, &bb);
      int rA = r0 + (lane >> 3);
      if ((lane & 7) == 0) {
        kvrow[rA]   = a  + bqkv_q[DD + rA];
        kvrow[rA+8] = bb + bqkv_q[DD + rA + 8];
      }
    }
    __syncthreads();
    kvq[(size_t)j*512 + tid]       = kvrow[tid];
    kvq[(size_t)j*512 + 256 + tid] = kvrow[256 + tid];
  }
}

// ---------------- K2: front half — block (n, half): q, t, scores, softmax, iaw-partial, u, ctx
__global__ __launch_bounds__(512)
void k_front(const float* __restrict__ patches, const float* __restrict__ pT,
             const float* __restrict__ et_g,
             const float* __restrict__ Wqkv_e, const float* __restrict__ bqkv_e,
             float* __restrict__ ctx_ws, float* __restrict__ iawp)
{
  const int b = blockIdx.x, n = b >> 1, half = b & 1;
  const int tid = threadIdx.x, w = tid >> 6, lane = tid & 63;
  __shared__ float attS[4][NP];    // 16 KB
  __shared__ float up[2][4][DD];   // 8 KB (first tpart, then u partials)
  __shared__ float tS[4][DD];      // 4 KB (t, then u)
  __shared__ float xL[DD], qL[128];

  const float* Wn = Wqkv_e + (size_t)n*(3*DD*DD);
  const float* bn = bqkv_e + (size_t)n*(3*DD);

  if (tid < DD) xL[tid] = et_g[(size_t)n*DD + tid];
  __syncthreads();

  // ---- q: global rows [half*128 + w*16, +16)  (streams Wq, NT) ----
  {
    float4 xf[8]; preload8(xL, lane, xf);
    float a, bb;
    pass16<true>(Wn, DD, half*128 + w*16, lane, xf, &a, &bb);
    int rL = w*16 + (lane >> 3);
    if ((lane & 7) == 0) {
      qL[rL]   = a  + bn[half*128 + rL];
      qL[rL+8] = bb + bn[half*128 + rL + 8];
    }
  }
  // ---- t: wave w -> head_local w>>1, k-half w&1 (reads exactly its own qL rows) ----
  {
    const int hl = w >> 1, kh = w & 1;
    const float* Wk = Wn + (size_t)DD*DD + (size_t)(half*128 + hl*32 + kh*16)*DD;
    float4 acc = make_float4(0.f,0.f,0.f,0.f);
    #pragma unroll
    for (int dc = 0; dc < 4; ++dc) {
      float4 q4 = *(const float4*)&qL[hl*32 + kh*16 + dc*4];
      float4 r0v = ldnt4(&Wk[(size_t)(dc*4+0)*DD + 4*lane]);
      float4 r1v = ldnt4(&Wk[(size_t)(dc*4+1)*DD + 4*lane]);
      float4 r2v = ldnt4(&Wk[(size_t)(dc*4+2)*DD + 4*lane]);
      float4 r3v = ldnt4(&Wk[(size_t)(dc*4+3)*DD + 4*lane]);
      acc.x += q4.x*r0v.x + q4.y*r1v.x + q4.z*r2v.x + q4.w*r3v.x;
      acc.y += q4.x*r0v.y + q4.y*r1v.y + q4.z*r2v.y + q4.w*r3v.y;
      acc.z += q4.x*r0v.z + q4.y*r1v.z + q4.z*r2v.z + q4.w*r3v.z;
      acc.w += q4.x*r0v.w + q4.y*r1v.w + q4.z*r2v.w + q4.w*r3v.w;
    }
    *(float4*)&up[kh][hl][4*lane] = acc;
  }
  __syncthreads();
  {
    float* tf = &tS[0][0];
    const float* t0 = &up[0][0][0];
    const float* t1 = &up[1][0][0];
    for (int idx = tid; idx < 4*DD; idx += 512) tf[idx] = t0[idx] + t1[idx];
  }
  __syncthreads();

  // ---- scores: thread owns patches 2*tid, 2*tid+1 (pT stays L2-resident) ----
  {
    float acc0[4], acc1[4];
    #pragma unroll
    for (int hl = 0; hl < 4; ++hl) { acc0[hl] = 0.f; acc1[hl] = 0.f; }
    #pragma unroll 2
    for (int c4 = 0; c4 < 64; ++c4) {
      float2 pv[4];
      #pragma unroll
      for (int j = 0; j < 4; ++j)
        pv[j] = *(const float2*)&pT[(size_t)(c4*4+j)*NP + 2*tid];
      #pragma unroll
      for (int hl = 0; hl < 4; ++hl) {
        float4 t4 = *(const float4*)&tS[hl][c4*4];
        acc0[hl] += t4.x*pv[0].x + t4.y*pv[1].x + t4.z*pv[2].x + t4.w*pv[3].x;
        acc1[hl] += t4.x*pv[0].y + t4.y*pv[1].y + t4.z*pv[2].y + t4.w*pv[3].y;
      }
    }
    #pragma unroll
    for (int hl = 0; hl < 4; ++hl) {
      attS[hl][2*tid]   = acc0[hl];
      attS[hl][2*tid+1] = acc1[hl];
    }
  }
  __syncthreads();
  // ---- softmax: waves 0-3 (wave == local head) ----
  if (w < 4) {
    const int hl = w;
    float v[16];
    #pragma unroll
    for (int k = 0; k < 16; ++k) v[k] = attS[hl][k*64 + lane] * SCALE;
    float mx = v[0];
    #pragma unroll
    for (int k = 1; k < 16; ++k) mx = fmaxf(mx, v[k]);
    mx = wred_max(mx);
    float sum = 0.f;
    #pragma unroll
    for (int k = 0; k < 16; ++k) { v[k] = __expf(v[k] - mx); sum += v[k]; }
    sum = wred_sum(sum);
    float rinv = 1.f / sum;
    #pragma unroll
    for (int k = 0; k < 16; ++k) attS[hl][k*64 + lane] = v[k] * rinv;
  }
  __syncthreads();
  // ---- iaw partial (sum of 4 local heads) ----
  #pragma unroll
  for (int rep = 0; rep < 2; ++rep) {
    int p = rep*512 + tid;
    float s = attS[0][p] + attS[1][p] + attS[2][p] + attS[3][p];
    iawp[(size_t)(n*2 + half)*NP + p] = s;
  }
  // ---- u: 2-way split-k over patch halves; 4 waves cover 256 cols ----
  {
    const int ph = w >> 2, c = (w & 3)*64 + lane;
    float ua[4] = {0.f, 0.f, 0.f, 0.f};
    const float* pb = patches + (size_t)ph*512*DD + c;
    #pragma unroll 2
    for (int pc = 0; pc < 128; ++pc) {
      float p0 = pb[(size_t)(pc*4+0)*DD];
      float p1 = pb[(size_t)(pc*4+1)*DD];
      float p2 = pb[(size_t)(pc*4+2)*DD];
      float p3 = pb[(size_t)(pc*4+3)*DD];
      #pragma unroll
      for (int hl = 0; hl < 4; ++hl) {
        float4 a4 = *(const float4*)&attS[hl][ph*512 + pc*4];
        ua[hl] += a4.x*p0 + a4.y*p1 + a4.z*p2 + a4.w*p3;
      }
    }
    #pragma unroll
    for (int hl = 0; hl < 4; ++hl) up[ph][hl][c] = ua[hl];
  }
  __syncthreads();
  if (tid < DD) {
    #pragma unroll
    for (int hl = 0; hl < 4; ++hl) tS[hl][tid] = up[0][hl][tid] + up[1][hl][tid];
  }
  __syncthreads();

  // ---- ctx: global rows [half*128 + w*16, +16) of Wv (NT); head_local = w>>1 ----
  {
    float4 xf[8]; preload8(&tS[w >> 1][0], lane, xf);
    float a, bb;
    pass16<true>(Wn + (size_t)2*DD*DD, DD, half*128 + w*16, lane, xf, &a, &bb);
    int rL = w*16 + (lane >> 3);
    if ((lane & 7) == 0) {
      ctx_ws[(size_t)n*DD + half*128 + rL]     = a  + bn[2*DD + half*128 + rL];
      ctx_ws[(size_t)n*DD + half*128 + rL + 8] = bb + bn[2*DD + half*128 + rL + 8];
    }
  }
}

// ---------------- K3: iaw combine + out-proj + LN1 + qca + LN2 + FFN + qkv_s ----------------
__global__ __launch_bounds__(1024)
void k_mid(const float* __restrict__ ctx_ws, const float* __restrict__ iawp,
           const float* __restrict__ et_g,
           const float* __restrict__ Wo_e, const float* __restrict__ bo_e,
           const float* __restrict__ kvq,
           const float* __restrict__ Wqkv_q, const float* __restrict__ bqkv_q,
           const float* __restrict__ Wo_q, const float* __restrict__ bo_q,
           const float* __restrict__ W1, const float* __restrict__ b1,
           const float* __restrict__ W2, const float* __restrict__ b2,
           const float* __restrict__ Wqkv_s, const float* __restrict__ bqkv_s,
           const float* __restrict__ ln1g, const float* __restrict__ ln1b,
           const float* __restrict__ ln2g, const float* __restrict__ ln2b,
           float* __restrict__ er_g, float* __restrict__ qkvs_g,
           float* __restrict__ iaw)
{
  const int n = blockIdx.x, tid = threadIdx.x, w = tid >> 6, lane = tid & 63;
  __shared__ float xL[DD], qL[DD], ctxL[DD], resS[DD], attq[NH][NQ], red2[2];
  __shared__ float hb[1024], qrow[768];

  // iaw combine (independent)
  iaw[(size_t)n*NP + tid] = 0.125f * (iawp[(size_t)(n*2)*NP + tid] + iawp[(size_t)(n*2+1)*NP + tid]);

  if (tid < DD) { ctxL[tid] = ctx_ws[(size_t)n*DD + tid]; xL[tid] = et_g[(size_t)n*DD + tid]; }
  __syncthreads();

  // ---- out = ctx @ Wo^T + bo + et (streams Wo_e, NT); LN1 -> xL ----
  {
    float4 xf[8]; preload8(ctxL, lane, xf);
    const float* Won = Wo_e + (size_t)n*DD*DD;
    float a, b;
    pass16<true>(Won, DD, w*16, lane, xf, &a, &b);
    int rA = w*16 + (lane >> 3);
    if ((lane & 7) == 0) {
      resS[rA]   = a + bo_e[(size_t)n*DD + rA]     + xL[rA];
      resS[rA+8] = b + bo_e[(size_t)n*DD + rA + 8] + xL[rA+8];
    }
  }
  layernorm_store(resS, xL, ln1g, ln1b, red2, tid, w, lane);
  __syncthreads();

  // ---- qca: q projection (shared weights: cached) ----
  {
    float4 xf[8]; preload8(xL, lane, xf);
    float a, b;
    pass16<false>(Wqkv_q, DD, w*16, lane, xf, &a, &b);
    int rA = w*16 + (lane >> 3);
    if ((lane & 7) == 0) { qL[rA] = a + bqkv_q[rA]; qL[rA+8] = b + bqkv_q[rA+8]; }
  }
  __syncthreads();
  // ---- qca: attention over 64 kv (waves 0-7) ----
  if (w < 8) {
    const int h = w, j = lane;
    float4 q4[8];
    #pragma unroll
    for (int m = 0; m < 8; ++m) q4[m] = *(const float4*)&qL[h*32 + 4*m];
    const float* kj = kvq + (size_t)j*512 + h*32;
    float s = 0.f;
    #pragma unroll
    for (int m = 0; m < 8; ++m) s += dot4(*(const float4*)&kj[4*m], q4[m]);
    s *= SCALE;
    float mx = wred_max(s);
    float p = __expf(s - mx);
    float sum = wred_sum(p);
    attq[h][j] = p / sum;
  }
  __syncthreads();
  if (tid < DD) {
    const int rr = tid, h = rr >> 5;
    float acc = 0.f;
    #pragma unroll 4
    for (int j4 = 0; j4 < 16; ++j4) {
      float4 a4 = *(const float4*)&attq[h][j4*4];
      acc += a4.x * kvq[(size_t)(j4*4+0)*512 + DD + rr]
           + a4.y * kvq[(size_t)(j4*4+1)*512 + DD + rr]
           + a4.z * kvq[(size_t)(j4*4+2)*512 + DD + rr]
           + a4.w * kvq[(size_t)(j4*4+3)*512 + DD + rr];
    }
    ctxL[rr] = acc;
  }
  __syncthreads();
  // ---- qca: out proj + residual; LN2 -> xL ----
  {
    float4 xf[8]; preload8(ctxL, lane, xf);
    float a, b;
    pass16<false>(Wo_q, DD, w*16, lane, xf, &a, &b);
    int rA = w*16 + (lane >> 3);
    if ((lane & 7) == 0) { resS[rA] = a + bo_q[rA] + xL[rA]; resS[rA+8] = b + bo_q[rA+8] + xL[rA+8]; }
  }
  layernorm_store(resS, xL, ln2g, ln2b, red2, tid, w, lane);
  __syncthreads();

  // ---- FFN1 -> hb ----
  {
    float4 xf[8]; preload8(xL, lane, xf);
    #pragma unroll
    for (int g = 0; g < 4; ++g) {
      int r0 = w*64 + g*16;
      float a, b;
      pass16<false>(W1, DD, r0, lane, xf, &a, &b);
      int rA = r0 + (lane >> 3);
      if ((lane & 7) == 0) { hb[rA] = fmaxf(a + b1[rA], 0.f); hb[rA+8] = fmaxf(b + b1[rA+8], 0.f); }
    }
  }
  __syncthreads();
  // ---- FFN2 (K=1024 in 4 chunks) -> qL = expert_refined ----
  {
    float accA = 0.f, accB = 0.f;
    #pragma unroll
    for (int kc = 0; kc < 4; ++kc) {
      float4 xh[8]; preload8(hb + kc*256, lane, xh);
      float a, b;
      pass16<false>(W2 + kc*256, 1024, w*16, lane, xh, &a, &b);
      accA += a; accB += b;
    }
    int rA = w*16 + (lane >> 3);
    if ((lane & 7) == 0) { qL[rA] = accA + b2[rA]; qL[rA+8] = accB + b2[rA+8]; }
  }
  __syncthreads();
  // ---- qkv_s projection (768 rows) ----
  {
    float4 xf[8]; preload8(qL, lane, xf);
    #pragma unroll
    for (int g = 0; g < 3; ++g) {
      int r0 = w*48 + g*16;
      float a, b;
      pass16<false>(Wqkv_s, DD, r0, lane, xf, &a, &b);
      int rA = r0 + (lane >> 3);
      if ((lane & 7) == 0) { qrow[rA] = a + bqkv_s[rA]; qrow[rA+8] = b + bqkv_s[rA+8]; }
    }
  }
  __syncthreads();
  if (tid < 768) qkvs_g[(size_t)n*768 + tid] = qrow[tid];
  if (tid < DD)  er_g[(size_t)n*DD + tid]   = qL[tid];
}

// ---------------- K4: self attention + LN3 ----------------
__global__ __launch_bounds__(1024)
void k_sa(const float* __restrict__ er, const float* __restrict__ qkvs,
          const float* __restrict__ Wo_s, const float* __restrict__ bo_s,
          const float* __restrict__ ln3g, const float* __restrict__ ln3b,
          float* __restrict__ ef)
{
  const int i = blockIdx.x, tid = threadIdx.x, w = tid >> 6, lane = tid & 63;
  __shared__ float x[DD], attl[NH][256], ctxp[4][DD], resS[DD], red2[2];
  if (tid < DD) x[tid] = er[(size_t)i*DD + tid];
  {
    const int h = w & 7, kh = w >> 3;
    float4 q4[8];
    #pragma unroll
    for (int m = 0; m < 8; ++m) q4[m] = *(const float4*)&qkvs[(size_t)i*768 + h*32 + 4*m];
    #pragma unroll
    for (int rep = 0; rep < 2; ++rep) {
      int j = kh*128 + rep*64 + lane;
      const float* kj = qkvs + (size_t)j*768 + DD + h*32;
      float4 k4[8];
      #pragma unroll
      for (int m = 0; m < 8; ++m) k4[m] = *(const float4*)&kj[4*m];
      float s = 0.f;
      #pragma unroll
      for (int m = 0; m < 8; ++m) s += dot4(k4[m], q4[m]);
      attl[h][j] = s * SCALE;
    }
  }
  __syncthreads();
  if (w < 8) {
    const int h = w;
    float v0 = attl[h][lane], v1 = attl[h][lane+64], v2 = attl[h][lane+128], v3 = attl[h][lane+192];
    float mx = wred_max(fmaxf(fmaxf(v0,v1), fmaxf(v2,v3)));
    float e0 = __expf(v0-mx), e1 = __expf(v1-mx), e2 = __expf(v2-mx), e3 = __expf(v3-mx);
    float sum = wred_sum(e0+e1+e2+e3);
    float r = 1.f/sum;
    attl[h][lane] = e0*r; attl[h][lane+64] = e1*r; attl[h][lane+128] = e2*r; attl[h][lane+192] = e3*r;
  }
  __syncthreads();
  {
    const int rr = tid & 255, qtr = tid >> 8, h = rr >> 5;
    float acc = 0.f;
    #pragma unroll 4
    for (int j4 = qtr*16; j4 < qtr*16 + 16; ++j4) {
      float4 a4 = *(const float4*)&attl[h][j4*4];
      acc += a4.x * qkvs[(size_t)(j4*4+0)*768 + 512 + rr]
           + a4.y * qkvs[(size_t)(j4*4+1)*768 + 512 + rr]
           + a4.z * qkvs[(size_t)(j4*4+2)*768 + 512 + rr]
           + a4.w * qkvs[(size_t)(j4*4+3)*768 + 512 + rr];
    }
    ctxp[qtr][rr] = acc;
  }
  __syncthreads();
  {
    float4 xf[8];
    const int o = (lane & 7)*4;
    #pragma unroll
    for (int cc = 0; cc < 8; ++cc) {
      float4 a = *(const float4*)&ctxp[0][cc*32 + o];
      float4 b = *(const float4*)&ctxp[1][cc*32 + o];
      float4 c = *(const float4*)&ctxp[2][cc*32 + o];
      float4 d = *(const float4*)&ctxp[3][cc*32 + o];
      xf[cc] = make_float4(a.x+b.x+c.x+d.x, a.y+b.y+c.y+d.y,
                           a.z+b.z+c.z+d.z, a.w+b.w+c.w+d.w);
    }
    float a, b;
    pass16<false>(Wo_s, DD, w*16, lane, xf, &a, &b);
    int rA = w*16 + (lane >> 3);
    if ((lane & 7) == 0) { resS[rA] = a + bo_s[rA] + x[rA]; resS[rA+8] = b + bo_s[rA+8] + x[rA+8]; }
  }
  layernorm_store(resS, ef + (size_t)i*DD, ln3g, ln3b, red2, tid, w, lane);
}

extern "C" void kernel_launch(void* const* d_in, const int* in_sizes, int n_in,
                              void* d_out, int out_size, void* d_ws, size_t ws_size,
                              hipStream_t stream) {
  const float* patches = (const float*)d_in[0];
  const float* et      = (const float*)d_in[1];
  const float* qe      = (const float*)d_in[2];
  const float* Wqkv_e  = (const float*)d_in[3];
  const float* bqkv_e  = (const float*)d_in[4];
  const float* Wo_e    = (const float*)d_in[5];
  const float* bo_e    = (const float*)d_in[6];
  const float* Wqkv_q  = (const float*)d_in[7];
  const float* bqkv_q  = (const float*)d_in[8];
  const float* Wo_q    = (const float*)d_in[9];
  const float* bo_q    = (const float*)d_in[10];
  const float* Wqkv_s  = (const float*)d_in[11];
  const float* bqkv_s  = (const float*)d_in[12];
  const float* Wo_s    = (const float*)d_in[13];
  const float* bo_s    = (const float*)d_in[14];
  const float* W1      = (const float*)d_in[15];
  const float* b1      = (const float*)d_in[16];
  const float* W2      = (const float*)d_in[17];
  const float* b2      = (const float*)d_in[18];
  const float* ln1g = (const float*)d_in[19]; const float* ln1b = (const float*)d_in[20];
  const float* ln2g = (const float*)d_in[21]; const float* ln2b = (const float*)d_in[22];
  const float* ln3g = (const float*)d_in[23]; const float* ln3b = (const float*)d_in[24];

  float* ef  = (float*)d_out;
  float* iaw = (float*)d_out + 65536;

  float* ws     = (float*)d_ws;
  float* pT     = ws;                   // 262144 floats
  float* kvq    = ws + 262144;          // 32768
  float* ctx_ws = ws + 294912;          // 65536
  float* iawp   = ws + 360448;          // 524288 (2 halves x 256 x 1024)
  float* er     = ws + 884736;          // 65536
  float* qkvs   = ws + 950272;          // 196608

  k_pre<<<320, 256, 0, stream>>>(patches, pT, qe, Wqkv_q, bqkv_q, kvq);
  k_front<<<512, 512, 0, stream>>>(patches, pT, et, Wqkv_e, bqkv_e, ctx_ws, iawp);
  k_mid<<<256, 1024, 0, stream>>>(ctx_ws, iawp, et, Wo_e, bo_e,
                                  kvq, Wqkv_q, bqkv_q, Wo_q, bo_q,
                                  W1, b1, W2, b2, Wqkv_s, bqkv_s,
                                  ln1g, ln1b, ln2g, ln2b,
                                  er, qkvs, iaw);
  k_sa<<<256, 1024, 0, stream>>>(er, qkvs, Wo_s, bo_s, ln3g, ln3b, ef);
}

// Round 7
// 155.279 us; speedup vs baseline: 1.2273x; 1.2273x over previous
//
#include <hip/hip_runtime.h>

#define DD 256      // embed dim
#define NH 8        // heads
#define NP 1024     // patches
#define NQ 64       // query embeddings
#define SCALE 0.17677669529663687f

typedef float f32x4v __attribute__((ext_vector_type(4)));
typedef __bf16 bfv8 __attribute__((ext_vector_type(8)));

union BF8 { bfv8 v; unsigned short u16[8]; uint4 q; };

__device__ __forceinline__ float wred_sum(float p) {
  #pragma unroll
  for (int m = 32; m; m >>= 1) p += __shfl_xor(p, m);
  return p;
}
__device__ __forceinline__ float wred_max(float p) {
  #pragma unroll
  for (int m = 32; m; m >>= 1) p = fmaxf(p, __shfl_xor(p, m));
  return p;
}
__device__ __forceinline__ float red8(float p) {
  p += __shfl_xor(p, 1);
  p += __shfl_xor(p, 2);
  p += __shfl_xor(p, 4);
  return p;
}
__device__ __forceinline__ float dot4(float4 a, float4 b) {
  return a.x*b.x + a.y*b.y + a.z*b.z + a.w*b.w;
}
__device__ __forceinline__ float4 ldnt4(const float* p) {
  f32x4v v = __builtin_nontemporal_load((const f32x4v*)p);
  return make_float4(v.x, v.y, v.z, v.w);
}
// f32 -> bf16 round-to-nearest-even
__device__ __forceinline__ unsigned short f2b(float f) {
  unsigned int u = __float_as_uint(f);
  u += 0x7fffu + ((u >> 16) & 1u);
  return (unsigned short)(u >> 16);
}
__device__ __forceinline__ BF8 cvt8(float4 a, float4 b) {
  BF8 r;
  r.u16[0]=f2b(a.x); r.u16[1]=f2b(a.y); r.u16[2]=f2b(a.z); r.u16[3]=f2b(a.w);
  r.u16[4]=f2b(b.x); r.u16[5]=f2b(b.y); r.u16[6]=f2b(b.z); r.u16[7]=f2b(b.w);
  return r;
}
__device__ __forceinline__ f32x4v mfma16(BF8 a, BF8 b, f32x4v c) {
  return __builtin_amdgcn_mfma_f32_16x16x32_bf16(a.v, b.v, c, 0, 0, 0);
}

__device__ __forceinline__ void preload8(const float* x, int lane, float4* xf) {
  const int o = (lane & 7) * 4;
  #pragma unroll
  for (int cc = 0; cc < 8; ++cc) xf[cc] = *(const float4*)&x[cc*32 + o];
}
// 16 rows per pass: rows r0+(lane>>3), r0+8+(lane>>3); 16 dwordx4 in flight.
template<bool NT>
__device__ __forceinline__ void pass16(const float* __restrict__ W, int ldk,
                                       int r0, int lane, const float4* xf,
                                       float* outA, float* outB) {
  const float* baseA = W + (size_t)(r0 + (lane >> 3))*ldk + (lane & 7)*4;
  const float* baseB = baseA + (size_t)8*ldk;
  float4 wa[8], wb[8];
  #pragma unroll
  for (int cc = 0; cc < 8; ++cc) wa[cc] = NT ? ldnt4(&baseA[cc*32]) : *(const float4*)&baseA[cc*32];
  #pragma unroll
  for (int cc = 0; cc < 8; ++cc) wb[cc] = NT ? ldnt4(&baseB[cc*32]) : *(const float4*)&baseB[cc*32];
  float a = 0.f, b = 0.f;
  #pragma unroll
  for (int cc = 0; cc < 8; ++cc) { a += dot4(wa[cc], xf[cc]); b += dot4(wb[cc], xf[cc]); }
  *outA = red8(a); *outB = red8(b);
}

__device__ __forceinline__ void layernorm_store(const float* buf, float* outp,
                                                const float* g, const float* b,
                                                float* red, int tid, int wid, int lane)
{
  __syncthreads();
  if (wid == 0) {
    float s = buf[lane] + buf[lane+64] + buf[lane+128] + buf[lane+192];
    s = wred_sum(s);
    if (!lane) red[0] = s * (1.f/256.f);
  }
  __syncthreads();
  float mn = red[0];
  if (wid == 0) {
    float d0 = buf[lane]-mn, d1 = buf[lane+64]-mn, d2 = buf[lane+128]-mn, d3 = buf[lane+192]-mn;
    float s = d0*d0 + d1*d1 + d2*d2 + d3*d3;
    s = wred_sum(s);
    if (!lane) red[1] = rsqrtf(s * (1.f/256.f) + 1e-5f);
  }
  __syncthreads();
  if (tid < 256) outp[tid] = (buf[tid] - mn) * red[1] * g[tid] + b[tid];
}

// ---------------- K1: build MFMA B-fragment buffers + kvq ----------------
// pTB   (scores B: K=c, N=p): tile T=kt*64+nt; elem[l][j] = patches[nt*16+(l&15)][kt*32+(l>>4)*8+j]
// patchesB (u B: K=p, N=c):   tile T=kt*16+nt; elem[l][j] = patches[kt*32+(l>>4)*8+j][nt*16+(l&15)]
__global__ __launch_bounds__(256)
void k_pre(const float* __restrict__ patches, uint4* __restrict__ pTB,
           uint4* __restrict__ patchesB,
           const float* __restrict__ qe, const float* __restrict__ Wqkv_q,
           const float* __restrict__ bqkv_q, float* __restrict__ kvq)
{
  const int b = blockIdx.x, tid = threadIdx.x;
  if (b < 128) {
    const int T = b*4 + (tid >> 6), l = tid & 63;
    const int kt = T >> 6, nt = T & 63;
    const int row = nt*16 + (l & 15), col = kt*32 + (l >> 4)*8;
    float4 a = *(const float4*)&patches[(size_t)row*DD + col];
    float4 c = *(const float4*)&patches[(size_t)row*DD + col + 4];
    pTB[(size_t)T*64 + l] = cvt8(a, c).q;
  } else if (b < 256) {
    const int T = (b - 128)*4 + (tid >> 6), l = tid & 63;
    const int kt = T >> 4, nt = T & 15;
    const int col = nt*16 + (l & 15), p0 = kt*32 + (l >> 4)*8;
    float v[8];
    #pragma unroll
    for (int j = 0; j < 8; ++j) v[j] = patches[(size_t)(p0 + j)*DD + col];
    BF8 r;
    #pragma unroll
    for (int j = 0; j < 8; ++j) r.u16[j] = f2b(v[j]);
    patchesB[(size_t)T*64 + l] = r.q;
  } else {
    __shared__ float x[DD], kvrow[512];
    const int j = b - 256, w = tid >> 6, lane = tid & 63;
    if (tid < DD) x[tid] = qe[j*DD + tid];
    __syncthreads();
    float4 xf[8]; preload8(x, lane, xf);
    #pragma unroll
    for (int g = 0; g < 8; ++g) {
      int r0 = w*128 + g*16;
      float a, bb;
      pass16<false>(Wqkv_q + (size_t)DD*DD, DD, r0, lane, xf, &a, &bb);
      int rA = r0 + (lane >> 3);
      if ((lane & 7) == 0) {
        kvrow[rA]   = a  + bqkv_q[DD + rA];
        kvrow[rA+8] = bb + bqkv_q[DD + rA + 8];
      }
    }
    __syncthreads();
    kvq[(size_t)j*512 + tid]       = kvrow[tid];
    kvq[(size_t)j*512 + 256 + tid] = kvrow[256 + tid];
  }
}

// ---------------- K2: per-expert front: q, t, MFMA scores, softmax, iaw, MFMA u, ctx ---------
__global__ __launch_bounds__(512)
void k_front(const float* __restrict__ et_g,
             const float* __restrict__ Wqkv_e, const float* __restrict__ bqkv_e,
             const uint4* __restrict__ pTB, const uint4* __restrict__ patchesB,
             float* __restrict__ ctx_ws, float* __restrict__ iaw)
{
  const int n = blockIdx.x, tid = threadIdx.x, w = tid >> 6, lane = tid & 63;
  __shared__ float xL[DD], qL[DD];
  __shared__ float attS[NH][NP];                    // 32 KB (f32 scores/probs)
  __shared__ __align__(16) char uAbuf[32768];       // union: tS f32[16][260] / attB uint4[16][128]
  __shared__ float uS[NH][DD];                      // 8 KB
  float (*tS)[260] = (float (*)[260])uAbuf;
  uint4 (*attB)[128] = (uint4 (*)[128])uAbuf;

  const float* Wn = Wqkv_e + (size_t)n*(3*DD*DD);
  const float* bn = bqkv_e + (size_t)n*(3*DD);

  if (tid < DD) xL[tid] = et_g[(size_t)n*DD + tid];
  __syncthreads();

  // ---- q-proj (streams Wq): wave w -> rows [w*32, +32) ----
  {
    float4 xf[8]; preload8(xL, lane, xf);
    #pragma unroll
    for (int g = 0; g < 2; ++g) {
      float a, bq;
      pass16<true>(Wn, DD, w*32 + g*16, lane, xf, &a, &bq);
      int rA = w*32 + g*16 + (lane >> 3);
      if ((lane & 7) == 0) { qL[rA] = a + bn[rA]; qL[rA+8] = bq + bn[rA+8]; }
    }
  }
  // ---- t (streams Wk): wave w == head w reads its OWN qL rows (no barrier) ----
  {
    const float* Wk = Wn + (size_t)DD*DD + (size_t)w*32*DD;
    float4 acc = make_float4(0.f, 0.f, 0.f, 0.f);
    #pragma unroll 8
    for (int r = 0; r < 32; ++r) {
      float qs = qL[w*32 + r];
      float4 wv = ldnt4(&Wk[(size_t)r*DD + 4*lane]);
      acc.x += qs*wv.x; acc.y += qs*wv.y; acc.z += qs*wv.z; acc.w += qs*wv.w;
    }
    *(float4*)&tS[w][4*lane] = acc;     // rows 0-7; rows 8-15 garbage (C rows 8-15 discarded)
  }
  __syncthreads();

  // ---- scores A-frags from tS (stride 260 -> 2-way-free b128 reads) ----
  BF8 afr[8];
  {
    const int rr = lane & 15, ko = (lane >> 4)*8;
    #pragma unroll
    for (int kt = 0; kt < 8; ++kt) {
      float4 a = *(const float4*)&tS[rr][kt*32 + ko];
      float4 c = *(const float4*)&tS[rr][kt*32 + ko + 4];
      afr[kt] = cvt8(a, c);
    }
  }
  // ---- scores MFMA: wave w -> n-tiles [w*8, +8); K=256 in 8 steps ----
  {
    #pragma unroll
    for (int t8 = 0; t8 < 8; ++t8) {
      const int nt = w*8 + t8;
      f32x4v acc = {0.f, 0.f, 0.f, 0.f};
      #pragma unroll
      for (int kt = 0; kt < 8; ++kt) {
        BF8 bb; bb.q = pTB[(size_t)(kt*64 + nt)*64 + lane];
        acc = mfma16(afr[kt], bb, acc);
      }
      if (lane < 32) {
        const int r0 = (lane >> 4)*4, cc = nt*16 + (lane & 15);
        #pragma unroll
        for (int i = 0; i < 4; ++i) attS[r0 + i][cc] = acc[i];
      }
    }
  }
  __syncthreads();

  // ---- softmax rows 0-7 (wave == row), normalize in place ----
  {
    const int h = w;
    float v[16];
    #pragma unroll
    for (int k = 0; k < 16; ++k) v[k] = attS[h][k*64 + lane] * SCALE;
    float mx = v[0];
    #pragma unroll
    for (int k = 1; k < 16; ++k) mx = fmaxf(mx, v[k]);
    mx = wred_max(mx);
    float sum = 0.f;
    #pragma unroll
    for (int k = 0; k < 16; ++k) { v[k] = __expf(v[k] - mx); sum += v[k]; }
    sum = wred_sum(sum);
    float rinv = 1.f / sum;
    #pragma unroll
    for (int k = 0; k < 16; ++k) attS[h][k*64 + lane] = v[k] * rinv;
  }
  __syncthreads();

  // ---- iaw head-mean + repack att -> bf16 A-layout (XOR chunk swizzle) ----
  #pragma unroll
  for (int rep = 0; rep < 2; ++rep) {
    int p = rep*512 + tid;
    float s = 0.f;
    #pragma unroll
    for (int h = 0; h < NH; ++h) s += attS[h][p];
    iaw[(size_t)n*NP + p] = s * 0.125f;
  }
  #pragma unroll
  for (int rep = 0; rep < 2; ++rep) {
    int C = rep*512 + tid;            // 1024 chunks: row 0-7, 128 chunks each
    int row = C >> 7, c = C & 127;
    float4 a = *(const float4*)&attS[row][c*8];
    float4 b = *(const float4*)&attS[row][c*8 + 4];
    int swz = (c & ~7) | ((c ^ row) & 7);
    attB[row][swz] = cvt8(a, b).q;
  }
  __syncthreads();

  // ---- u MFMA: wave w -> n-tiles 2w, 2w+1; K=1024 in 32 steps ----
  {
    const int nt0 = 2*w, nt1 = 2*w + 1;
    f32x4v acc0 = {0.f,0.f,0.f,0.f}, acc1 = {0.f,0.f,0.f,0.f};
    const int rr = lane & 15, cq = lane >> 4;
    #pragma unroll 8
    for (int kt = 0; kt < 32; ++kt) {
      int cc = kt*4 + cq;
      int swz = (cc & ~7) | ((cc ^ rr) & 7);
      BF8 a;  a.q  = attB[rr][swz];
      BF8 b0; b0.q = patchesB[(size_t)(kt*16 + nt0)*64 + lane];
      BF8 b1; b1.q = patchesB[(size_t)(kt*16 + nt1)*64 + lane];
      acc0 = mfma16(a, b0, acc0);
      acc1 = mfma16(a, b1, acc1);
    }
    if (lane < 32) {
      const int r0 = (lane >> 4)*4;
      #pragma unroll
      for (int i = 0; i < 4; ++i) {
        uS[r0+i][nt0*16 + (lane & 15)] = acc0[i];
        uS[r0+i][nt1*16 + (lane & 15)] = acc1[i];
      }
    }
  }
  __syncthreads();

  // ---- ctx (streams Wv): wave w -> rows [w*32, +32) == head w ----
  {
    float4 xf[8]; preload8(&uS[w][0], lane, xf);
    #pragma unroll
    for (int g = 0; g < 2; ++g) {
      float a, bq;
      pass16<true>(Wn + (size_t)2*DD*DD, DD, w*32 + g*16, lane, xf, &a, &bq);
      int rA = w*32 + g*16 + (lane >> 3);
      if ((lane & 7) == 0) {
        ctx_ws[(size_t)n*DD + rA]     = a  + bn[2*DD + rA];
        ctx_ws[(size_t)n*DD + rA + 8] = bq + bn[2*DD + rA + 8];
      }
    }
  }
}

// ---------------- K3: out-proj + LN1 + qca + LN2 + FFN + qkv_s ----------------
__global__ __launch_bounds__(1024)
void k_mid(const float* __restrict__ ctx_ws, const float* __restrict__ et_g,
           const float* __restrict__ Wo_e, const float* __restrict__ bo_e,
           const float* __restrict__ kvq,
           const float* __restrict__ Wqkv_q, const float* __restrict__ bqkv_q,
           const float* __restrict__ Wo_q, const float* __restrict__ bo_q,
           const float* __restrict__ W1, const float* __restrict__ b1,
           const float* __restrict__ W2, const float* __restrict__ b2,
           const float* __restrict__ Wqkv_s, const float* __restrict__ bqkv_s,
           const float* __restrict__ ln1g, const float* __restrict__ ln1b,
           const float* __restrict__ ln2g, const float* __restrict__ ln2b,
           float* __restrict__ er_g, float* __restrict__ qkvs_g)
{
  const int n = blockIdx.x, tid = threadIdx.x, w = tid >> 6, lane = tid & 63;
  __shared__ float xL[DD], qL[DD], ctxL[DD], resS[DD], attq[NH][NQ], red2[2];
  __shared__ float hb[1024], qrow[768];

  if (tid < DD) { ctxL[tid] = ctx_ws[(size_t)n*DD + tid]; xL[tid] = et_g[(size_t)n*DD + tid]; }
  __syncthreads();

  // out = ctx @ Wo^T + bo + et (streams Wo_e, NT); LN1 -> xL
  {
    float4 xf[8]; preload8(ctxL, lane, xf);
    const float* Won = Wo_e + (size_t)n*DD*DD;
    float a, b;
    pass16<true>(Won, DD, w*16, lane, xf, &a, &b);
    int rA = w*16 + (lane >> 3);
    if ((lane & 7) == 0) {
      resS[rA]   = a + bo_e[(size_t)n*DD + rA]     + xL[rA];
      resS[rA+8] = b + bo_e[(size_t)n*DD + rA + 8] + xL[rA+8];
    }
  }
  layernorm_store(resS, xL, ln1g, ln1b, red2, tid, w, lane);
  __syncthreads();

  // qca q-proj
  {
    float4 xf[8]; preload8(xL, lane, xf);
    float a, b;
    pass16<false>(Wqkv_q, DD, w*16, lane, xf, &a, &b);
    int rA = w*16 + (lane >> 3);
    if ((lane & 7) == 0) { qL[rA] = a + bqkv_q[rA]; qL[rA+8] = b + bqkv_q[rA+8]; }
  }
  __syncthreads();
  if (w < 8) {
    const int h = w, j = lane;
    float4 q4[8];
    #pragma unroll
    for (int m = 0; m < 8; ++m) q4[m] = *(const float4*)&qL[h*32 + 4*m];
    const float* kj = kvq + (size_t)j*512 + h*32;
    float s = 0.f;
    #pragma unroll
    for (int m = 0; m < 8; ++m) s += dot4(*(const float4*)&kj[4*m], q4[m]);
    s *= SCALE;
    float mx = wred_max(s);
    float p = __expf(s - mx);
    float sum = wred_sum(p);
    attq[h][j] = p / sum;
  }
  __syncthreads();
  if (tid < DD) {
    const int rr = tid, h = rr >> 5;
    float acc = 0.f;
    #pragma unroll 4
    for (int j4 = 0; j4 < 16; ++j4) {
      float4 a4 = *(const float4*)&attq[h][j4*4];
      acc += a4.x * kvq[(size_t)(j4*4+0)*512 + DD + rr]
           + a4.y * kvq[(size_t)(j4*4+1)*512 + DD + rr]
           + a4.z * kvq[(size_t)(j4*4+2)*512 + DD + rr]
           + a4.w * kvq[(size_t)(j4*4+3)*512 + DD + rr];
    }
    ctxL[rr] = acc;
  }
  __syncthreads();
  {
    float4 xf[8]; preload8(ctxL, lane, xf);
    float a, b;
    pass16<false>(Wo_q, DD, w*16, lane, xf, &a, &b);
    int rA = w*16 + (lane >> 3);
    if ((lane & 7) == 0) { resS[rA] = a + bo_q[rA] + xL[rA]; resS[rA+8] = b + bo_q[rA+8] + xL[rA+8]; }
  }
  layernorm_store(resS, xL, ln2g, ln2b, red2, tid, w, lane);
  __syncthreads();

  // FFN1
  {
    float4 xf[8]; preload8(xL, lane, xf);
    #pragma unroll
    for (int g = 0; g < 4; ++g) {
      int r0 = w*64 + g*16;
      float a, b;
      pass16<false>(W1, DD, r0, lane, xf, &a, &b);
      int rA = r0 + (lane >> 3);
      if ((lane & 7) == 0) { hb[rA] = fmaxf(a + b1[rA], 0.f); hb[rA+8] = fmaxf(b + b1[rA+8], 0.f); }
    }
  }
  __syncthreads();
  // FFN2
  {
    float accA = 0.f, accB = 0.f;
    #pragma unroll
    for (int kc = 0; kc < 4; ++kc) {
      float4 xh[8]; preload8(hb + kc*256, lane, xh);
      float a, b;
      pass16<false>(W2 + kc*256, 1024, w*16, lane, xh, &a, &b);
      accA += a; accB += b;
    }
    int rA = w*16 + (lane >> 3);
    if ((lane & 7) == 0) { qL[rA] = accA + b2[rA]; qL[rA+8] = accB + b2[rA+8]; }
  }
  __syncthreads();
  // qkv_s projection
  {
    float4 xf[8]; preload8(qL, lane, xf);
    #pragma unroll
    for (int g = 0; g < 3; ++g) {
      int r0 = w*48 + g*16;
      float a, b;
      pass16<false>(Wqkv_s, DD, r0, lane, xf, &a, &b);
      int rA = r0 + (lane >> 3);
      if ((lane & 7) == 0) { qrow[rA] = a + bqkv_s[rA]; qrow[rA+8] = b + bqkv_s[rA+8]; }
    }
  }
  __syncthreads();
  if (tid < 768) qkvs_g[(size_t)n*768 + tid] = qrow[tid];
  if (tid < DD)  er_g[(size_t)n*DD + tid]   = qL[tid];
}

// ---------------- K4: self attention + LN3 ----------------
__global__ __launch_bounds__(1024)
void k_sa(const float* __restrict__ er, const float* __restrict__ qkvs,
          const float* __restrict__ Wo_s, const float* __restrict__ bo_s,
          const float* __restrict__ ln3g, const float* __restrict__ ln3b,
          float* __restrict__ ef)
{
  const int i = blockIdx.x, tid = threadIdx.x, w = tid >> 6, lane = tid & 63;
  __shared__ float x[DD], attl[NH][256], ctxp[4][DD], resS[DD], red2[2];
  if (tid < DD) x[tid] = er[(size_t)i*DD + tid];
  {
    const int h = w & 7, kh = w >> 3;
    float4 q4[8];
    #pragma unroll
    for (int m = 0; m < 8; ++m) q4[m] = *(const float4*)&qkvs[(size_t)i*768 + h*32 + 4*m];
    #pragma unroll
    for (int rep = 0; rep < 2; ++rep) {
      int j = kh*128 + rep*64 + lane;
      const float* kj = qkvs + (size_t)j*768 + DD + h*32;
      float4 k4[8];
      #pragma unroll
      for (int m = 0; m < 8; ++m) k4[m] = *(const float4*)&kj[4*m];
      float s = 0.f;
      #pragma unroll
      for (int m = 0; m < 8; ++m) s += dot4(k4[m], q4[m]);
      attl[h][j] = s * SCALE;
    }
  }
  __syncthreads();
  if (w < 8) {
    const int h = w;
    float v0 = attl[h][lane], v1 = attl[h][lane+64], v2 = attl[h][lane+128], v3 = attl[h][lane+192];
    float mx = wred_max(fmaxf(fmaxf(v0,v1), fmaxf(v2,v3)));
    float e0 = __expf(v0-mx), e1 = __expf(v1-mx), e2 = __expf(v2-mx), e3 = __expf(v3-mx);
    float sum = wred_sum(e0+e1+e2+e3);
    float r = 1.f/sum;
    attl[h][lane] = e0*r; attl[h][lane+64] = e1*r; attl[h][lane+128] = e2*r; attl[h][lane+192] = e3*r;
  }
  __syncthreads();
  {
    const int rr = tid & 255, qtr = tid >> 8, h = rr >> 5;
    float acc = 0.f;
    #pragma unroll 4
    for (int j4 = qtr*16; j4 < qtr*16 + 16; ++j4) {
      float4 a4 = *(const float4*)&attl[h][j4*4];
      acc += a4.x * qkvs[(size_t)(j4*4+0)*768 + 512 + rr]
           + a4.y * qkvs[(size_t)(j4*4+1)*768 + 512 + rr]
           + a4.z * qkvs[(size_t)(j4*4+2)*768 + 512 + rr]
           + a4.w * qkvs[(size_t)(j4*4+3)*768 + 512 + rr];
    }
    ctxp[qtr][rr] = acc;
  }
  __syncthreads();
  {
    float4 xf[8];
    const int o = (lane & 7)*4;
    #pragma unroll
    for (int cc = 0; cc < 8; ++cc) {
      float4 a = *(const float4*)&ctxp[0][cc*32 + o];
      float4 b = *(const float4*)&ctxp[1][cc*32 + o];
      float4 c = *(const float4*)&ctxp[2][cc*32 + o];
      float4 d = *(const float4*)&ctxp[3][cc*32 + o];
      xf[cc] = make_float4(a.x+b.x+c.x+d.x, a.y+b.y+c.y+d.y,
                           a.z+b.z+c.z+d.z, a.w+b.w+c.w+d.w);
    }
    float a, b;
    pass16<false>(Wo_s, DD, w*16, lane, xf, &a, &b);
    int rA = w*16 + (lane >> 3);
    if ((lane & 7) == 0) { resS[rA] = a + bo_s[rA] + x[rA]; resS[rA+8] = b + bo_s[rA+8] + x[rA+8]; }
  }
  layernorm_store(resS, ef + (size_t)i*DD, ln3g, ln3b, red2, tid, w, lane);
}

extern "C" void kernel_launch(void* const* d_in, const int* in_sizes, int n_in,
                              void* d_out, int out_size, void* d_ws, size_t ws_size,
                              hipStream_t stream) {
  const float* patches = (const float*)d_in[0];
  const float* et      = (const float*)d_in[1];
  const float* qe      = (const float*)d_in[2];
  const float* Wqkv_e  = (const float*)d_in[3];
  const float* bqkv_e  = (const float*)d_in[4];
  const float* Wo_e    = (const float*)d_in[5];
  const float* bo_e    = (const float*)d_in[6];
  const float* Wqkv_q  = (const float*)d_in[7];
  const float* bqkv_q  = (const float*)d_in[8];
  const float* Wo_q    = (const float*)d_in[9];
  const float* bo_q    = (const float*)d_in[10];
  const float* Wqkv_s  = (const float*)d_in[11];
  const float* bqkv_s  = (const float*)d_in[12];
  const float* Wo_s    = (const float*)d_in[13];
  const float* bo_s    = (const float*)d_in[14];
  const float* W1      = (const float*)d_in[15];
  const float* b1      = (const float*)d_in[16];
  const float* W2      = (const float*)d_in[17];
  const float* b2      = (const float*)d_in[18];
  const float* ln1g = (const float*)d_in[19]; const float* ln1b = (const float*)d_in[20];
  const float* ln2g = (const float*)d_in[21]; const float* ln2b = (const float*)d_in[22];
  const float* ln3g = (const float*)d_in[23]; const float* ln3b = (const float*)d_in[24];

  float* ef  = (float*)d_out;
  float* iaw = (float*)d_out + 65536;

  float* ws       = (float*)d_ws;
  uint4* pTB      = (uint4*)ws;             // 512 tiles * 64 lanes * 16B = 512 KB
  uint4* patchesB = (uint4*)(ws + 131072);  // 512 KB
  float* kvq      = ws + 262144;            // 32768 floats
  float* ctx_ws   = ws + 294912;            // 65536
  float* er       = ws + 360448;            // 65536
  float* qkvs     = ws + 425984;            // 196608

  k_pre<<<320, 256, 0, stream>>>(patches, pTB, patchesB, qe, Wqkv_q, bqkv_q, kvq);
  k_front<<<256, 512, 0, stream>>>(et, Wqkv_e, bqkv_e, pTB, patchesB, ctx_ws, iaw);
  k_mid<<<256, 1024, 0, stream>>>(ctx_ws, et, Wo_e, bo_e,
                                  kvq, Wqkv_q, bqkv_q, Wo_q, bo_q,
                                  W1, b1, W2, b2, Wqkv_s, bqkv_s,
                                  ln1g, ln1b, ln2g, ln2b, er, qkvs);
  k_sa<<<256, 1024, 0, stream>>>(er, qkvs, Wo_s, bo_s, ln3g, ln3b, ef);
}

// Round 8
// 136.542 us; speedup vs baseline: 1.3957x; 1.1372x over previous
//
#include <hip/hip_runtime.h>

#define DD 256      // embed dim
#define NH 8        // heads
#define NP 1024     // patches
#define NQ 64       // query embeddings
#define SCALE 0.17677669529663687f

typedef float f32x4v __attribute__((ext_vector_type(4)));
typedef __bf16 bfv8 __attribute__((ext_vector_type(8)));

union BF8 { bfv8 v; unsigned short u16[8]; uint4 q; };

__device__ __forceinline__ float wred_sum(float p) {
  #pragma unroll
  for (int m = 32; m; m >>= 1) p += __shfl_xor(p, m);
  return p;
}
__device__ __forceinline__ float wred_max(float p) {
  #pragma unroll
  for (int m = 32; m; m >>= 1) p = fmaxf(p, __shfl_xor(p, m));
  return p;
}
__device__ __forceinline__ float red8(float p) {
  p += __shfl_xor(p, 1);
  p += __shfl_xor(p, 2);
  p += __shfl_xor(p, 4);
  return p;
}
__device__ __forceinline__ float dot4(float4 a, float4 b) {
  return a.x*b.x + a.y*b.y + a.z*b.z + a.w*b.w;
}
// f32 -> bf16 round-to-nearest-even
__device__ __forceinline__ unsigned short f2b(float f) {
  unsigned int u = __float_as_uint(f);
  u += 0x7fffu + ((u >> 16) & 1u);
  return (unsigned short)(u >> 16);
}
__device__ __forceinline__ BF8 cvt8(float4 a, float4 b) {
  BF8 r;
  r.u16[0]=f2b(a.x); r.u16[1]=f2b(a.y); r.u16[2]=f2b(a.z); r.u16[3]=f2b(a.w);
  r.u16[4]=f2b(b.x); r.u16[5]=f2b(b.y); r.u16[6]=f2b(b.z); r.u16[7]=f2b(b.w);
  return r;
}
__device__ __forceinline__ f32x4v mfma16(BF8 a, BF8 b, f32x4v c) {
  return __builtin_amdgcn_mfma_f32_16x16x32_bf16(a.v, b.v, c, 0, 0, 0);
}
// bf16 pair -> 2 f32 (elem order: low u16 first)
__device__ __forceinline__ float2 b2f2(unsigned int u) {
  return make_float2(__uint_as_float(u << 16), __uint_as_float(u & 0xffff0000u));
}
__device__ __forceinline__ float dotb8(uint4 w, float4 x0, float4 x1) {
  float2 p0 = b2f2(w.x), p1 = b2f2(w.y), p2 = b2f2(w.z), p3 = b2f2(w.w);
  return p0.x*x0.x + p0.y*x0.y + p1.x*x0.z + p1.y*x0.w
       + p2.x*x1.x + p2.y*x1.y + p3.x*x1.z + p3.y*x1.w;
}

__device__ __forceinline__ void preload8(const float* x, int lane, float4* xf) {
  const int o = (lane & 7) * 4;
  #pragma unroll
  for (int cc = 0; cc < 8; ++cc) xf[cc] = *(const float4*)&x[cc*32 + o];
}
// f32 weights: 16 rows/pass, rows r0+(lane>>3), +8; 16 dwordx4 in flight.
__device__ __forceinline__ void pass16(const float* __restrict__ W, int ldk,
                                       int r0, int lane, const float4* xf,
                                       float* outA, float* outB) {
  const float* baseA = W + (size_t)(r0 + (lane >> 3))*ldk + (lane & 7)*4;
  const float* baseB = baseA + (size_t)8*ldk;
  float4 wa[8], wb[8];
  #pragma unroll
  for (int cc = 0; cc < 8; ++cc) wa[cc] = *(const float4*)&baseA[cc*32];
  #pragma unroll
  for (int cc = 0; cc < 8; ++cc) wb[cc] = *(const float4*)&baseB[cc*32];
  float a = 0.f, b = 0.f;
  #pragma unroll
  for (int cc = 0; cc < 8; ++cc) { a += dot4(wa[cc], xf[cc]); b += dot4(wb[cc], xf[cc]); }
  *outA = red8(a); *outB = red8(b);
}
// bf16 weights: x fragment layout for 8-lane groups, 8 elems/chunk
__device__ __forceinline__ void preload8b(const float* x, int lane, float4* xf) {
  const int o = (lane & 7) * 8;
  #pragma unroll
  for (int cc = 0; cc < 4; ++cc) {
    xf[2*cc]   = *(const float4*)&x[cc*64 + o];
    xf[2*cc+1] = *(const float4*)&x[cc*64 + o + 4];
  }
}
// bf16 weights row-major [N][ldk]: 16 rows/pass, 8 dwordx4 in flight (half bytes of pass16)
__device__ __forceinline__ void pass16b(const unsigned short* __restrict__ W, int ldk,
                                        int r0, int lane, const float4* xf,
                                        float* outA, float* outB) {
  const unsigned short* baseA = W + (size_t)(r0 + (lane >> 3))*ldk + (lane & 7)*8;
  const unsigned short* baseB = baseA + (size_t)8*ldk;
  uint4 wa[4], wb[4];
  #pragma unroll
  for (int cc = 0; cc < 4; ++cc) wa[cc] = *(const uint4*)&baseA[cc*64];
  #pragma unroll
  for (int cc = 0; cc < 4; ++cc) wb[cc] = *(const uint4*)&baseB[cc*64];
  float a = 0.f, b = 0.f;
  #pragma unroll
  for (int cc = 0; cc < 4; ++cc) {
    a += dotb8(wa[cc], xf[2*cc], xf[2*cc+1]);
    b += dotb8(wb[cc], xf[2*cc], xf[2*cc+1]);
  }
  *outA = red8(a); *outB = red8(b);
}

__device__ __forceinline__ void layernorm_store(const float* buf, float* outp,
                                                const float* g, const float* b,
                                                float* red, int tid, int wid, int lane)
{
  __syncthreads();
  if (wid == 0) {
    float s = buf[lane] + buf[lane+64] + buf[lane+128] + buf[lane+192];
    s = wred_sum(s);
    if (!lane) red[0] = s * (1.f/256.f);
  }
  __syncthreads();
  float mn = red[0];
  if (wid == 0) {
    float d0 = buf[lane]-mn, d1 = buf[lane+64]-mn, d2 = buf[lane+128]-mn, d3 = buf[lane+192]-mn;
    float s = d0*d0 + d1*d1 + d2*d2 + d3*d3;
    s = wred_sum(s);
    if (!lane) red[1] = rsqrtf(s * (1.f/256.f) + 1e-5f);
  }
  __syncthreads();
  if (tid < 256) outp[tid] = (buf[tid] - mn) * red[1] * g[tid] + b[tid];
}

// ---------------- K1: MFMA B-frag buffers + kvq + bf16 tail-weight conversion ----------------
__global__ __launch_bounds__(256)
void k_pre(const float* __restrict__ patches, uint4* __restrict__ pTB,
           uint4* __restrict__ patchesB,
           const float* __restrict__ qe, const float* __restrict__ Wqkv_q,
           const float* __restrict__ bqkv_q, float* __restrict__ kvq,
           const float* __restrict__ Wo_q, const float* __restrict__ W1,
           const float* __restrict__ W2, const float* __restrict__ Wqkv_s,
           unsigned short* __restrict__ wsB)
{
  const int b = blockIdx.x, tid = threadIdx.x;
  if (b < 128) {
    const int T = b*4 + (tid >> 6), l = tid & 63;
    const int kt = T >> 6, nt = T & 63;
    const int row = nt*16 + (l & 15), col = kt*32 + (l >> 4)*8;
    float4 a = *(const float4*)&patches[(size_t)row*DD + col];
    float4 c = *(const float4*)&patches[(size_t)row*DD + col + 4];
    pTB[(size_t)T*64 + l] = cvt8(a, c).q;
  } else if (b < 256) {
    const int T = (b - 128)*4 + (tid >> 6), l = tid & 63;
    const int kt = T >> 4, nt = T & 15;
    const int col = nt*16 + (l & 15), p0 = kt*32 + (l >> 4)*8;
    float v[8];
    #pragma unroll
    for (int j = 0; j < 8; ++j) v[j] = patches[(size_t)(p0 + j)*DD + col];
    BF8 r;
    #pragma unroll
    for (int j = 0; j < 8; ++j) r.u16[j] = f2b(v[j]);
    patchesB[(size_t)T*64 + l] = r.q;
  } else if (b < 320) {
    __shared__ float x[DD], kvrow[512];
    const int j = b - 256, w = tid >> 6, lane = tid & 63;
    if (tid < DD) x[tid] = qe[j*DD + tid];
    __syncthreads();
    float4 xf[8]; preload8(x, lane, xf);
    #pragma unroll
    for (int g = 0; g < 8; ++g) {
      int r0 = w*128 + g*16;
      float a, bb;
      pass16(Wqkv_q + (size_t)DD*DD, DD, r0, lane, xf, &a, &bb);
      int rA = r0 + (lane >> 3);
      if ((lane & 7) == 0) {
        kvrow[rA]   = a  + bqkv_q[DD + rA];
        kvrow[rA+8] = bb + bqkv_q[DD + rA + 8];
      }
    }
    __syncthreads();
    kvq[(size_t)j*512 + tid]       = kvrow[tid];
    kvq[(size_t)j*512 + 256 + tid] = kvrow[256 + tid];
  } else {
    // bf16 conversion of shared tail weights: 106496 items of 8 floats
    const int gid = (b - 320)*256 + tid;
    const float* src;
    size_t dof;
    if      (gid < 8192)  { src = Wqkv_q + (size_t)gid*8;           dof = (size_t)gid*8; }            // Wq_q @0
    else if (gid < 16384) { src = Wo_q   + (size_t)(gid-8192)*8;    dof = 65536  + (size_t)(gid-8192)*8; }
    else if (gid < 49152) { src = W1     + (size_t)(gid-16384)*8;   dof = 131072 + (size_t)(gid-16384)*8; }
    else if (gid < 81920) { src = W2     + (size_t)(gid-49152)*8;   dof = 393216 + (size_t)(gid-49152)*8; }
    else                  { src = Wqkv_s + (size_t)(gid-81920)*8;   dof = 655360 + (size_t)(gid-81920)*8; }
    float4 a = *(const float4*)&src[0];
    float4 c = *(const float4*)&src[4];
    *(uint4*)&wsB[dof] = cvt8(a, c).q;
  }
}

// ---------------- K2: per-expert: q, t, MFMA scores, softmax, iaw, MFMA u, ctx, out-proj, LN1
__global__ __launch_bounds__(512)
void k_front(const float* __restrict__ et_g,
             const float* __restrict__ Wqkv_e, const float* __restrict__ bqkv_e,
             const float* __restrict__ Wo_e, const float* __restrict__ bo_e,
             const uint4* __restrict__ pTB, const uint4* __restrict__ patchesB,
             const float* __restrict__ ln1g, const float* __restrict__ ln1b,
             float* __restrict__ aln_g, float* __restrict__ iaw)
{
  const int n = blockIdx.x, tid = threadIdx.x, w = tid >> 6, lane = tid & 63;
  __shared__ float xL[DD], qL[DD], ctxL[DD], resS[DD], red2[2];
  __shared__ float attS[NH][NP];                    // 32 KB
  __shared__ __align__(16) char uAbuf[32768];       // tS f32[16][260] / attB uint4[16][128]
  __shared__ float uS[NH][DD];                      // 8 KB
  float (*tS)[260] = (float (*)[260])uAbuf;
  uint4 (*attB)[128] = (uint4 (*)[128])uAbuf;

  const float* Wn = Wqkv_e + (size_t)n*(3*DD*DD);
  const float* bn = bqkv_e + (size_t)n*(3*DD);

  if (tid < DD) xL[tid] = et_g[(size_t)n*DD + tid];
  __syncthreads();

  // q-proj (streams Wq): wave w -> rows [w*32, +32)
  {
    float4 xf[8]; preload8(xL, lane, xf);
    #pragma unroll
    for (int g = 0; g < 2; ++g) {
      float a, bq;
      pass16(Wn, DD, w*32 + g*16, lane, xf, &a, &bq);
      int rA = w*32 + g*16 + (lane >> 3);
      if ((lane & 7) == 0) { qL[rA] = a + bn[rA]; qL[rA+8] = bq + bn[rA+8]; }
    }
  }
  // t (streams Wk): wave w == head w reads its OWN qL rows (no barrier needed)
  {
    const float* Wk = Wn + (size_t)DD*DD + (size_t)w*32*DD;
    float4 acc = make_float4(0.f, 0.f, 0.f, 0.f);
    #pragma unroll 8
    for (int r = 0; r < 32; ++r) {
      float qs = qL[w*32 + r];
      float4 wv = *(const float4*)&Wk[(size_t)r*DD + 4*lane];
      acc.x += qs*wv.x; acc.y += qs*wv.y; acc.z += qs*wv.z; acc.w += qs*wv.w;
    }
    *(float4*)&tS[w][4*lane] = acc;
  }
  __syncthreads();

  // scores A-frags from tS (stride 260 -> conflict-cheap b128 reads)
  BF8 afr[8];
  {
    const int rr = lane & 15, ko = (lane >> 4)*8;
    #pragma unroll
    for (int kt = 0; kt < 8; ++kt) {
      float4 a = *(const float4*)&tS[rr][kt*32 + ko];
      float4 c = *(const float4*)&tS[rr][kt*32 + ko + 4];
      afr[kt] = cvt8(a, c);
    }
  }
  // scores MFMA: wave w -> n-tiles [w*8, +8); K=256 in 8 steps
  {
    #pragma unroll
    for (int t8 = 0; t8 < 8; ++t8) {
      const int nt = w*8 + t8;
      f32x4v acc = {0.f, 0.f, 0.f, 0.f};
      #pragma unroll
      for (int kt = 0; kt < 8; ++kt) {
        BF8 bb; bb.q = pTB[(size_t)(kt*64 + nt)*64 + lane];
        acc = mfma16(afr[kt], bb, acc);
      }
      if (lane < 32) {
        const int r0 = (lane >> 4)*4, cc = nt*16 + (lane & 15);
        #pragma unroll
        for (int i = 0; i < 4; ++i) attS[r0 + i][cc] = acc[i];
      }
    }
  }
  __syncthreads();

  // softmax rows 0-7 (wave == head)
  {
    const int h = w;
    float v[16];
    #pragma unroll
    for (int k = 0; k < 16; ++k) v[k] = attS[h][k*64 + lane] * SCALE;
    float mx = v[0];
    #pragma unroll
    for (int k = 1; k < 16; ++k) mx = fmaxf(mx, v[k]);
    mx = wred_max(mx);
    float sum = 0.f;
    #pragma unroll
    for (int k = 0; k < 16; ++k) { v[k] = __expf(v[k] - mx); sum += v[k]; }
    sum = wred_sum(sum);
    float rinv = 1.f / sum;
    #pragma unroll
    for (int k = 0; k < 16; ++k) attS[h][k*64 + lane] = v[k] * rinv;
  }
  __syncthreads();

  // iaw head-mean + repack att -> bf16 A-layout (XOR chunk swizzle)
  #pragma unroll
  for (int rep = 0; rep < 2; ++rep) {
    int p = rep*512 + tid;
    float s = 0.f;
    #pragma unroll
    for (int h = 0; h < NH; ++h) s += attS[h][p];
    iaw[(size_t)n*NP + p] = s * 0.125f;
  }
  #pragma unroll
  for (int rep = 0; rep < 2; ++rep) {
    int C = rep*512 + tid;
    int row = C >> 7, c = C & 127;
    float4 a = *(const float4*)&attS[row][c*8];
    float4 b = *(const float4*)&attS[row][c*8 + 4];
    int swz = (c & ~7) | ((c ^ row) & 7);
    attB[row][swz] = cvt8(a, b).q;
  }
  __syncthreads();

  // u MFMA: wave w -> n-tiles 2w, 2w+1; K=1024 in 32 steps
  {
    const int nt0 = 2*w, nt1 = 2*w + 1;
    f32x4v acc0 = {0.f,0.f,0.f,0.f}, acc1 = {0.f,0.f,0.f,0.f};
    const int rr = lane & 15, cq = lane >> 4;
    #pragma unroll 8
    for (int kt = 0; kt < 32; ++kt) {
      int cc = kt*4 + cq;
      int swz = (cc & ~7) | ((cc ^ rr) & 7);
      BF8 a;  a.q  = attB[rr][swz];
      BF8 b0; b0.q = patchesB[(size_t)(kt*16 + nt0)*64 + lane];
      BF8 b1; b1.q = patchesB[(size_t)(kt*16 + nt1)*64 + lane];
      acc0 = mfma16(a, b0, acc0);
      acc1 = mfma16(a, b1, acc1);
    }
    if (lane < 32) {
      const int r0 = (lane >> 4)*4;
      #pragma unroll
      for (int i = 0; i < 4; ++i) {
        uS[r0+i][nt0*16 + (lane & 15)] = acc0[i];
        uS[r0+i][nt1*16 + (lane & 15)] = acc1[i];
      }
    }
  }
  __syncthreads();

  // ctx (streams Wv): wave w -> rows [w*32, +32) == head w
  {
    float4 xf[8]; preload8(&uS[w][0], lane, xf);
    #pragma unroll
    for (int g = 0; g < 2; ++g) {
      float a, bq;
      pass16(Wn + (size_t)2*DD*DD, DD, w*32 + g*16, lane, xf, &a, &bq);
      int rA = w*32 + g*16 + (lane >> 3);
      if ((lane & 7) == 0) { ctxL[rA] = a + bn[2*DD + rA]; ctxL[rA+8] = bq + bn[2*DD + rA + 8]; }
    }
  }
  __syncthreads();

  // out-proj (streams Wo_e) + residual(et) ; LN1 -> aln_g
  {
    float4 xf[8]; preload8(ctxL, lane, xf);
    const float* Won = Wo_e + (size_t)n*DD*DD;
    #pragma unroll
    for (int g = 0; g < 2; ++g) {
      float a, bq;
      pass16(Won, DD, w*32 + g*16, lane, xf, &a, &bq);
      int rA = w*32 + g*16 + (lane >> 3);
      if ((lane & 7) == 0) {
        resS[rA]   = a  + bo_e[(size_t)n*DD + rA]     + xL[rA];
        resS[rA+8] = bq + bo_e[(size_t)n*DD + rA + 8] + xL[rA+8];
      }
    }
  }
  layernorm_store(resS, aln_g + (size_t)n*DD, ln1g, ln1b, red2, tid, w, lane);
}

// ---------------- K3: tail with bf16 shared weights: qca + LN2 + FFN + qkv_s ----------------
__global__ __launch_bounds__(1024)
void k_mid(const float* __restrict__ aln, const float* __restrict__ kvq,
           const unsigned short* __restrict__ wsB,
           const float* __restrict__ bqkv_q, const float* __restrict__ bo_q,
           const float* __restrict__ b1, const float* __restrict__ b2,
           const float* __restrict__ bqkv_s,
           const float* __restrict__ ln2g, const float* __restrict__ ln2b,
           float* __restrict__ er_g, float* __restrict__ qkvs_g)
{
  const int n = blockIdx.x, tid = threadIdx.x, w = tid >> 6, lane = tid & 63;
  __shared__ float xL[DD], qL[DD], ctxL[DD], resS[DD], attq[NH][NQ], red2[2];
  __shared__ float hb[1024], qrow[768];
  const unsigned short* WqB  = wsB;            // [256][256]
  const unsigned short* WoqB = wsB + 65536;    // [256][256]
  const unsigned short* W1B  = wsB + 131072;   // [1024][256]
  const unsigned short* W2B  = wsB + 393216;   // [256][1024]
  const unsigned short* WsB  = wsB + 655360;   // [768][256]

  if (tid < DD) xL[tid] = aln[(size_t)n*DD + tid];
  __syncthreads();

  // qca q-proj: wave w -> rows [w*16, +16)
  {
    float4 xf[8]; preload8b(xL, lane, xf);
    float a, b;
    pass16b(WqB, DD, w*16, lane, xf, &a, &b);
    int rA = w*16 + (lane >> 3);
    if ((lane & 7) == 0) { qL[rA] = a + bqkv_q[rA]; qL[rA+8] = b + bqkv_q[rA+8]; }
  }
  __syncthreads();
  // attention over 64 kv (waves 0-7)
  if (w < 8) {
    const int h = w, j = lane;
    float4 q4[8];
    #pragma unroll
    for (int m = 0; m < 8; ++m) q4[m] = *(const float4*)&qL[h*32 + 4*m];
    const float* kj = kvq + (size_t)j*512 + h*32;
    float s = 0.f;
    #pragma unroll
    for (int m = 0; m < 8; ++m) s += dot4(*(const float4*)&kj[4*m], q4[m]);
    s *= SCALE;
    float mx = wred_max(s);
    float p = __expf(s - mx);
    float sum = wred_sum(p);
    attq[h][j] = p / sum;
  }
  __syncthreads();
  if (tid < DD) {
    const int rr = tid, h = rr >> 5;
    float acc = 0.f;
    #pragma unroll 4
    for (int j4 = 0; j4 < 16; ++j4) {
      float4 a4 = *(const float4*)&attq[h][j4*4];
      acc += a4.x * kvq[(size_t)(j4*4+0)*512 + DD + rr]
           + a4.y * kvq[(size_t)(j4*4+1)*512 + DD + rr]
           + a4.z * kvq[(size_t)(j4*4+2)*512 + DD + rr]
           + a4.w * kvq[(size_t)(j4*4+3)*512 + DD + rr];
    }
    ctxL[rr] = acc;
  }
  __syncthreads();
  // qca out-proj + residual; LN2 -> xL
  {
    float4 xf[8]; preload8b(ctxL, lane, xf);
    float a, b;
    pass16b(WoqB, DD, w*16, lane, xf, &a, &b);
    int rA = w*16 + (lane >> 3);
    if ((lane & 7) == 0) { resS[rA] = a + bo_q[rA] + xL[rA]; resS[rA+8] = b + bo_q[rA+8] + xL[rA+8]; }
  }
  layernorm_store(resS, xL, ln2g, ln2b, red2, tid, w, lane);
  __syncthreads();

  // FFN1: wave w -> rows [w*64, +64)
  {
    float4 xf[8]; preload8b(xL, lane, xf);
    #pragma unroll
    for (int g = 0; g < 4; ++g) {
      int r0 = w*64 + g*16;
      float a, b;
      pass16b(W1B, DD, r0, lane, xf, &a, &b);
      int rA = r0 + (lane >> 3);
      if ((lane & 7) == 0) { hb[rA] = fmaxf(a + b1[rA], 0.f); hb[rA+8] = fmaxf(b + b1[rA+8], 0.f); }
    }
  }
  __syncthreads();
  // FFN2 (K=1024 in 4 chunks): wave w -> rows [w*16, +16)
  {
    float accA = 0.f, accB = 0.f;
    #pragma unroll
    for (int kc = 0; kc < 4; ++kc) {
      float4 xh[8]; preload8b(hb + kc*256, lane, xh);
      float a, b;
      pass16b(W2B + kc*256, 1024, w*16, lane, xh, &a, &b);
      accA += a; accB += b;
    }
    int rA = w*16 + (lane >> 3);
    if ((lane & 7) == 0) { qL[rA] = accA + b2[rA]; qL[rA+8] = accB + b2[rA+8]; }
  }
  __syncthreads();
  // qkv_s projection: wave w -> rows [w*48, +48)
  {
    float4 xf[8]; preload8b(qL, lane, xf);
    #pragma unroll
    for (int g = 0; g < 3; ++g) {
      int r0 = w*48 + g*16;
      float a, b;
      pass16b(WsB, DD, r0, lane, xf, &a, &b);
      int rA = r0 + (lane >> 3);
      if ((lane & 7) == 0) { qrow[rA] = a + bqkv_s[rA]; qrow[rA+8] = b + bqkv_s[rA+8]; }
    }
  }
  __syncthreads();
  if (tid < 768) qkvs_g[(size_t)n*768 + tid] = qrow[tid];
  if (tid < DD)  er_g[(size_t)n*DD + tid]   = qL[tid];
}

// ---------------- K4: self attention + LN3 ----------------
__global__ __launch_bounds__(1024)
void k_sa(const float* __restrict__ er, const float* __restrict__ qkvs,
          const float* __restrict__ Wo_s, const float* __restrict__ bo_s,
          const float* __restrict__ ln3g, const float* __restrict__ ln3b,
          float* __restrict__ ef)
{
  const int i = blockIdx.x, tid = threadIdx.x, w = tid >> 6, lane = tid & 63;
  __shared__ float x[DD], attl[NH][256], ctxp[4][DD], resS[DD], red2[2];
  if (tid < DD) x[tid] = er[(size_t)i*DD + tid];
  {
    const int h = w & 7, kh = w >> 3;
    float4 q4[8];
    #pragma unroll
    for (int m = 0; m < 8; ++m) q4[m] = *(const float4*)&qkvs[(size_t)i*768 + h*32 + 4*m];
    #pragma unroll
    for (int rep = 0; rep < 2; ++rep) {
      int j = kh*128 + rep*64 + lane;
      const float* kj = qkvs + (size_t)j*768 + DD + h*32;
      float4 k4[8];
      #pragma unroll
      for (int m = 0; m < 8; ++m) k4[m] = *(const float4*)&kj[4*m];
      float s = 0.f;
      #pragma unroll
      for (int m = 0; m < 8; ++m) s += dot4(k4[m], q4[m]);
      attl[h][j] = s * SCALE;
    }
  }
  __syncthreads();
  if (w < 8) {
    const int h = w;
    float v0 = attl[h][lane], v1 = attl[h][lane+64], v2 = attl[h][lane+128], v3 = attl[h][lane+192];
    float mx = wred_max(fmaxf(fmaxf(v0,v1), fmaxf(v2,v3)));
    float e0 = __expf(v0-mx), e1 = __expf(v1-mx), e2 = __expf(v2-mx), e3 = __expf(v3-mx);
    float sum = wred_sum(e0+e1+e2+e3);
    float r = 1.f/sum;
    attl[h][lane] = e0*r; attl[h][lane+64] = e1*r; attl[h][lane+128] = e2*r; attl[h][lane+192] = e3*r;
  }
  __syncthreads();
  {
    const int rr = tid & 255, qtr = tid >> 8, h = rr >> 5;
    float acc = 0.f;
    #pragma unroll 4
    for (int j4 = qtr*16; j4 < qtr*16 + 16; ++j4) {
      float4 a4 = *(const float4*)&attl[h][j4*4];
      acc += a4.x * qkvs[(size_t)(j4*4+0)*768 + 512 + rr]
           + a4.y * qkvs[(size_t)(j4*4+1)*768 + 512 + rr]
           + a4.z * qkvs[(size_t)(j4*4+2)*768 + 512 + rr]
           + a4.w * qkvs[(size_t)(j4*4+3)*768 + 512 + rr];
    }
    ctxp[qtr][rr] = acc;
  }
  __syncthreads();
  {
    float4 xf[8];
    const int o = (lane & 7)*4;
    #pragma unroll
    for (int cc = 0; cc < 8; ++cc) {
      float4 a = *(const float4*)&ctxp[0][cc*32 + o];
      float4 b = *(const float4*)&ctxp[1][cc*32 + o];
      float4 c = *(const float4*)&ctxp[2][cc*32 + o];
      float4 d = *(const float4*)&ctxp[3][cc*32 + o];
      xf[cc] = make_float4(a.x+b.x+c.x+d.x, a.y+b.y+c.y+d.y,
                           a.z+b.z+c.z+d.z, a.w+b.w+c.w+d.w);
    }
    float a, b;
    pass16(Wo_s, DD, w*16, lane, xf, &a, &b);
    int rA = w*16 + (lane >> 3);
    if ((lane & 7) == 0) { resS[rA] = a + bo_s[rA] + x[rA]; resS[rA+8] = b + bo_s[rA+8] + x[rA+8]; }
  }
  layernorm_store(resS, ef + (size_t)i*DD, ln3g, ln3b, red2, tid, w, lane);
}

extern "C" void kernel_launch(void* const* d_in, const int* in_sizes, int n_in,
                              void* d_out, int out_size, void* d_ws, size_t ws_size,
                              hipStream_t stream) {
  const float* patches = (const float*)d_in[0];
  const float* et      = (const float*)d_in[1];
  const float* qe      = (const float*)d_in[2];
  const float* Wqkv_e  = (const float*)d_in[3];
  const float* bqkv_e  = (const float*)d_in[4];
  const float* Wo_e    = (const float*)d_in[5];
  const float* bo_e    = (const float*)d_in[6];
  const float* Wqkv_q  = (const float*)d_in[7];
  const float* bqkv_q  = (const float*)d_in[8];
  const float* Wo_q    = (const float*)d_in[9];
  const float* bo_q    = (const float*)d_in[10];
  const float* Wqkv_s  = (const float*)d_in[11];
  const float* bqkv_s  = (const float*)d_in[12];
  const float* Wo_s    = (const float*)d_in[13];
  const float* bo_s    = (const float*)d_in[14];
  const float* W1      = (const float*)d_in[15];
  const float* b1      = (const float*)d_in[16];
  const float* W2      = (const float*)d_in[17];
  const float* b2      = (const float*)d_in[18];
  const float* ln1g = (const float*)d_in[19]; const float* ln1b = (const float*)d_in[20];
  const float* ln2g = (const float*)d_in[21]; const float* ln2b = (const float*)d_in[22];
  const float* ln3g = (const float*)d_in[23]; const float* ln3b = (const float*)d_in[24];

  float* ef  = (float*)d_out;
  float* iaw = (float*)d_out + 65536;

  float* ws           = (float*)d_ws;
  uint4* pTB          = (uint4*)ws;             // 512 KB
  uint4* patchesB     = (uint4*)(ws + 131072);  // 512 KB
  float* kvq          = ws + 262144;            // 32768 floats
  float* aln          = ws + 294912;            // 65536
  float* er           = ws + 360448;            // 65536
  float* qkvs         = ws + 425984;            // 196608
  unsigned short* wsB = (unsigned short*)(ws + 622592);  // 851968 bf16 = 1.7 MB

  k_pre<<<736, 256, 0, stream>>>(patches, pTB, patchesB, qe, Wqkv_q, bqkv_q, kvq,
                                 Wo_q, W1, W2, Wqkv_s, wsB);
  k_front<<<256, 512, 0, stream>>>(et, Wqkv_e, bqkv_e, Wo_e, bo_e,
                                   pTB, patchesB, ln1g, ln1b, aln, iaw);
  k_mid<<<256, 1024, 0, stream>>>(aln, kvq, wsB, bqkv_q, bo_q, b1, b2, bqkv_s,
                                  ln2g, ln2b, er, qkvs);
  k_sa<<<256, 1024, 0, stream>>>(er, qkvs, Wo_s, bo_s, ln3g, ln3b, ef);
}